// Round 1
// 838.727 us; speedup vs baseline: 1.2401x; 1.2401x over previous
//
#include <hip/hip_runtime.h>
#include <math.h>

// Problem constants (fixed by setup_inputs)
#define B_ 8
#define C_ 2
#define T_ 1440000
#define F_ 1408            // ceil((T+M)/M) with M=1024
#define R_ 22528           // B*C*F
#define TARGET_HI 2731     // bits > 2730.667  <=>  int bits >= 2731

// ws byte offsets
#define OFF_CFH 0ull                     // f16 [k=1024][n=2048] hi   (4 MiB)
#define OFF_CFL (4ull << 20)             // f16 [k=1024][n=2048] lo   (4 MiB)
#define OFF_CIH (8ull << 20)             // f16 [n=2048][k=1024] hi   (4 MiB)
#define OFF_WF  (12ull << 20)            // f32 [2048]
#define OFF_CF  (13ull << 20)            // f32 [R_][1024] coeffs (92.3 MB)
#define OFF_DQ  (OFF_CF + (size_t)R_ * 1024 * 4)   // f16 [R_][1024] (46 MB)

typedef _Float16 f16x8 __attribute__((ext_vector_type(8)));
typedef _Float16 f16x4 __attribute__((ext_vector_type(4)));
typedef float f32x16 __attribute__((ext_vector_type(16)));

__device__ inline f32x16 mfma16(f16x8 a, f16x8 b, f32x16 c) {
  return __builtin_amdgcn_mfma_f32_32x32x16_f16(a, b, c, 0, 0, 0);
}

// async global->LDS, 16B per lane. LDS dest = uniform base + lane*16.
__device__ inline void gld_lds16(const void* g, void* l) {
  __builtin_amdgcn_global_load_lds(
      (const __attribute__((address_space(1))) void*)g,
      (__attribute__((address_space(3))) void*)l, 16, 0, 0);
}

// ---------------------------------------------------------------- tables ----
// CRITICAL: reproduce the reference's float32 phase arithmetic EXACTLY
// (f32(pi/M) * f32(n+512.5) -> f32 round -> * f32(k+0.5) -> f32 round -> cos).
__global__ __launch_bounds__(256) void init_tables(char* wsb) {
  _Float16* cfh = (_Float16*)(wsb + OFF_CFH);
  _Float16* cfl = (_Float16*)(wsb + OFF_CFL);
  _Float16* cih = (_Float16*)(wsb + OFF_CIH);
  float*    wf  = (float*)(wsb + OFF_WF);
  int idx = blockIdx.x * 256 + threadIdx.x;
  if (idx < 2097152) {
    int n = idx >> 10, k = idx & 1023;
    const float c0 = (float)(M_PI / 1024.0);
    float a  = (float)n + 0.5f + 512.0f;
    float t1 = c0 * a;
    float ph = t1 * ((float)k + 0.5f);
    float cm = (float)cos((double)ph);          // correctly-rounded cosf
    _Float16 h = (_Float16)cm;
    _Float16 l = (_Float16)(cm - (float)h);
    cfh[(size_t)k * 2048 + n] = h;
    cfl[(size_t)k * 2048 + n] = l;
    cih[(size_t)n * 1024 + k] = h;
  } else if (idx < 2097152 + 2048) {
    int n = idx - 2097152;
    const float c1 = (float)(M_PI / 2048.0);
    float ph = c1 * ((float)n + 0.5f);
    wf[n] = (float)sin((double)ph);
  }
}

// ----------------------------------------------- forward MDCT (f16 3-prod) --
// UNCHANGED this round (at the 2-barrier structural ceiling, MfmaUtil ~33%).
__global__ __launch_bounds__(256) void fwd_mfma(const float* __restrict__ audio,
                                                const char* __restrict__ wsb,
                                                float* __restrict__ coeffs) {
  __shared__ _Float16 Ah[128][40];
  __shared__ _Float16 Al[128][40];
  __shared__ _Float16 Bh[128][40];
  __shared__ _Float16 Bl[128][40];
  const _Float16* cfh = (const _Float16*)(wsb + OFF_CFH);
  const _Float16* cfl = (const _Float16*)(wsb + OFF_CFL);
  const float*    wf  = (const float*)(wsb + OFF_WF);

  int tid = threadIdx.x;
  int lane = tid & 63, wid = tid >> 6;
  int l31 = lane & 31, lHalf = lane >> 5;
  int waveM = wid >> 1, waveN = wid & 1;
  int rowTile = blockIdx.x * 128, colTile = blockIdx.y * 128;

  int sRow = tid >> 1;
  int sSeg = (tid & 1) << 4;
  int r = rowTile + sRow, bc = r / F_, f = r - bc * F_;
  const float* __restrict__ aud = audio + (size_t)bc * T_;
  int tBase = (f << 10) - 1024 + sSeg;
  const _Float16* bhp = cfh + (size_t)(colTile + sRow) * 2048 + sSeg;
  const _Float16* blp = cfl + (size_t)(colTile + sRow) * 2048 + sSeg;

  f32x16 acc[2][2];
#pragma unroll
  for (int i = 0; i < 2; i++)
#pragma unroll
    for (int j = 0; j < 2; j++)
#pragma unroll
      for (int e = 0; e < 16; e++) acc[i][j][e] = 0.f;

  for (int kt = 0; kt < 2048; kt += 32) {
    float av[16];
    int t0 = tBase + kt;
    if (t0 >= 0 && t0 + 16 <= T_) {
#pragma unroll
      for (int q = 0; q < 4; q++) {
        float4 x = *(const float4*)(aud + t0 + q * 4);
        av[q * 4 + 0] = x.x; av[q * 4 + 1] = x.y;
        av[q * 4 + 2] = x.z; av[q * 4 + 3] = x.w;
      }
    } else {
#pragma unroll
      for (int i = 0; i < 16; i++) {
        int t = t0 + i;
        av[i] = (t >= 0 && t < T_) ? aud[t] : 0.f;
      }
    }
    f16x8 vh[2], vl[2];
#pragma unroll
    for (int i = 0; i < 16; i++) {
      float v = av[i] * wf[kt + sSeg + i];
      _Float16 h = (_Float16)v;
      vh[i >> 3][i & 7] = h;
      vl[i >> 3][i & 7] = (_Float16)(v - (float)h);
    }
    float4 tb0 = *(const float4*)(bhp + kt);
    float4 tb1 = *(const float4*)(bhp + kt + 8);
    float4 tl0 = *(const float4*)(blp + kt);
    float4 tl1 = *(const float4*)(blp + kt + 8);

    __syncthreads();
    *(f16x8*)&Ah[sRow][sSeg]     = vh[0];
    *(f16x8*)&Ah[sRow][sSeg + 8] = vh[1];
    *(f16x8*)&Al[sRow][sSeg]     = vl[0];
    *(f16x8*)&Al[sRow][sSeg + 8] = vl[1];
    *(float4*)&Bh[sRow][sSeg]     = tb0;
    *(float4*)&Bh[sRow][sSeg + 8] = tb1;
    *(float4*)&Bl[sRow][sSeg]     = tl0;
    *(float4*)&Bl[sRow][sSeg + 8] = tl1;
    __syncthreads();

#pragma unroll
    for (int kc = 0; kc < 2; kc++) {
      int ko = kc * 16 + lHalf * 8;
      f16x8 a_h[2], a_l[2], b_h[2], b_l[2];
#pragma unroll
      for (int mi = 0; mi < 2; mi++) {
        a_h[mi] = *(const f16x8*)&Ah[waveM * 64 + mi * 32 + l31][ko];
        a_l[mi] = *(const f16x8*)&Al[waveM * 64 + mi * 32 + l31][ko];
      }
#pragma unroll
      for (int ni = 0; ni < 2; ni++) {
        b_h[ni] = *(const f16x8*)&Bh[waveN * 64 + ni * 32 + l31][ko];
        b_l[ni] = *(const f16x8*)&Bl[waveN * 64 + ni * 32 + l31][ko];
      }
#pragma unroll
      for (int mi = 0; mi < 2; mi++)
#pragma unroll
        for (int ni = 0; ni < 2; ni++) {
          acc[mi][ni] = mfma16(a_h[mi], b_h[ni], acc[mi][ni]);
          acc[mi][ni] = mfma16(a_h[mi], b_l[ni], acc[mi][ni]);
          acc[mi][ni] = mfma16(a_l[mi], b_h[ni], acc[mi][ni]);
        }
    }
  }

#pragma unroll
  for (int mi = 0; mi < 2; mi++)
#pragma unroll
    for (int ni = 0; ni < 2; ni++) {
      int col = colTile + waveN * 64 + ni * 32 + l31;
#pragma unroll
      for (int reg = 0; reg < 16; reg++) {
        int rowIn = (reg & 3) + 8 * (reg >> 2) + 4 * lHalf;
        int rr = rowTile + waveM * 64 + mi * 32 + rowIn;
        coeffs[(size_t)rr * 1024 + col] = acc[mi][ni][reg];
      }
    }
}

// --------------------------------------------- gain search + quant/dequant --
// REWRITTEN: one WAVE per (b,f) frame (no __syncthreads, butterfly reduce),
// powf eliminated: x^0.75 = sqrt(x)*sqrt(sqrt(x));  q^(4/3) = q*exp2(log2(q)/3)
// (branchless through q=0: log2(0)=-inf -> exp2 = 0 -> q43 = 0).
__global__ __launch_bounds__(256) void quantize(const float* __restrict__ cf,
                                                _Float16* __restrict__ dqh) {
  int wid = threadIdx.x >> 6, lane = threadIdx.x & 63;
  int bf = blockIdx.x * 4 + wid;     // 4 frames per 256-thread block
  int b = bf / F_, f = bf - b * F_;
  size_t base0 = ((size_t)(b * C_ + 0) * F_ + f) * 1024;
  size_t base1 = ((size_t)(b * C_ + 1) * F_ + f) * 1024;

  // 32 coeffs per lane: per channel 4 coalesced float4 loads (lane*4 + j*256)
  float x[32], ax75[32];
#pragma unroll
  for (int c = 0; c < 2; c++) {
    size_t bb = c ? base1 : base0;
#pragma unroll
    for (int j = 0; j < 4; j++) {
      float4 v = *(const float4*)(cf + bb + j * 256 + lane * 4);
      int o = c * 16 + j * 4;
      x[o + 0] = v.x; x[o + 1] = v.y; x[o + 2] = v.z; x[o + 3] = v.w;
    }
  }
#pragma unroll
  for (int u = 0; u < 32; u++) {
    float ax = fabsf(x[u]);
    float s  = sqrtf(ax);
    ax75[u]  = s * sqrtf(s);         // |x|^0.75, ~1-2 ulp of powf
  }

  int lo = 0, hi = 120;
#pragma unroll
  for (int it = 0; it < 8; it++) {
    int mid = (lo + hi) >> 1;
    float inv = exp2f(-0.1875f * (float)mid);
    int s = 0;
#pragma unroll
    for (int u = 0; u < 32; u++) {
      float qm = rintf(ax75[u] * inv);
      int iq = (int)qm;              // qm is small non-neg integer-valued
      s += (iq > 0) ? (33 - __clz(iq)) : 1;   // floor(log2 q)+2 else 1
    }
#pragma unroll
    for (int off = 1; off < 64; off <<= 1) s += __shfl_xor(s, off, 64);
    if (s >= TARGET_HI) lo = mid + 1; else hi = mid;   // uniform per wave
  }

  float scale = exp2f(0.25f * (float)hi);
  float rs    = exp2f(-0.25f * (float)hi);
#pragma unroll
  for (int c = 0; c < 2; c++) {
    size_t bb = c ? base1 : base0;
#pragma unroll
    for (int j = 0; j < 4; j++) {
      f16x4 o4;
#pragma unroll
      for (int e = 0; e < 4; e++) {
        int u = c * 16 + j * 4 + e;
        float ax  = fabsf(x[u]);
        float t   = ax * rs + 1e-9f;
        float s1  = sqrtf(t);
        float qs  = s1 * sqrtf(s1);              // (|x|/scale+eps)^0.75
        float q   = rintf(qs);
        float q43 = q * exp2f(__log2f(q) * (1.0f / 3.0f));  // q^(4/3)
        o4[e] = (_Float16)copysignf(q43 * scale, x[u]);
      }
      *(f16x4*)(dqh + bb + j * 256 + lane * 4) = o4;
    }
  }
}

// --------------------------------------- inverse MDCT (f16 1-prod) + OLA ----
// REWRITTEN: BK=64, block 128x256, wave tile 64x128 (6 ds_reads : 8 MFMA),
// staging via global_load_lds into LINEAR LDS with XOR-swizzle applied on the
// GLOBAL source address (rule #21: linear dest + inverse-swz source + swz read).
// Swizzle: within each 128B row of [.][64] f16, 16B unit u stored at u^(row&7).
// Read banks become 4*((uo^(l&7))&7): uniform 8-wrap = the b128 floor.
__global__ __launch_bounds__(256) void inv_mfma(const char* __restrict__ wsb,
                                               float* __restrict__ out) {
  __shared__ _Float16 Ad[128][64];   // 16 KB linear (swizzled units)
  __shared__ _Float16 Bd[256][64];   // 32 KB linear (swizzled units)
  const _Float16* dqh = (const _Float16*)(wsb + OFF_DQ);
  const _Float16* cih = (const _Float16*)(wsb + OFF_CIH);
  const float*    wf  = (const float*)(wsb + OFF_WF);

  int tid = threadIdx.x;
  int lane = tid & 63, wid = tid >> 6;
  int l31 = lane & 31, lHalf = lane >> 5;
  int waveM = wid >> 1, waveN = wid & 1;
  int rowTile = blockIdx.x * 128, colTile = blockIdx.y * 256;

  // staging: each 1KB wave-chunk covers 8 rows x 64 f16. lane l -> LDS byte
  // l*16 -> row chunk*8 + (l>>3), unit u' = l&7; source unit = u'^(row&7)
  // = (l&7)^(l>>3) (chunk*8 is 0 mod 8) -- lane-only, uniform across chunks.
  int srcRowOff = lane >> 3;
  int swz8 = ((lane & 7) ^ (lane >> 3)) << 3;   // element offset within row
  // wave wid: A chunks wid*4..+3 (rows wid*32..+31), B chunks wid*8..+7
  const _Float16* aSrc = dqh + (size_t)(rowTile + wid * 32 + srcRowOff) * 1024 + swz8;
  const _Float16* bSrc = cih + (size_t)(colTile + wid * 64 + srcRowOff) * 1024 + swz8;

  f32x16 acc[2][4];
#pragma unroll
  for (int i = 0; i < 2; i++)
#pragma unroll
    for (int j = 0; j < 4; j++)
#pragma unroll
      for (int e = 0; e < 16; e++) acc[i][j][e] = 0.f;

  int xoru = l31 & 7;                       // (row&7) for all fragment rows
  const char* adB = (const char*)&Ad[0][0];
  const char* bdB = (const char*)&Bd[0][0];
  int arow0 = (waveM * 64 + l31) << 7;      // byte offsets, row stride 128B
  int brow0 = (waveN * 128 + l31) << 7;

  for (int kt = 0; kt < 1024; kt += 64) {
    __syncthreads();                        // prior reads done before overwrite
#pragma unroll
    for (int i = 0; i < 4; i++)
      gld_lds16(aSrc + kt + (size_t)i * 8192, &Ad[wid * 32 + i * 8][0]);
#pragma unroll
    for (int i = 0; i < 8; i++)
      gld_lds16(bSrc + kt + (size_t)i * 8192, &Bd[wid * 64 + i * 8][0]);
    asm volatile("s_waitcnt vmcnt(0)" ::: "memory");
    __syncthreads();                        // all waves' chunks visible

#pragma unroll
    for (int kc = 0; kc < 4; kc++) {
      int su = (((kc * 2 + lHalf) ^ xoru) << 4);   // swizzled 16B unit
      f16x8 a0 = *(const f16x8*)(adB + arow0 + su);
      f16x8 a1 = *(const f16x8*)(adB + arow0 + 32 * 128 + su);
      f16x8 b0 = *(const f16x8*)(bdB + brow0 + su);
      f16x8 b1 = *(const f16x8*)(bdB + brow0 + 32 * 128 + su);
      f16x8 b2 = *(const f16x8*)(bdB + brow0 + 64 * 128 + su);
      f16x8 b3 = *(const f16x8*)(bdB + brow0 + 96 * 128 + su);
      acc[0][0] = mfma16(a0, b0, acc[0][0]);
      acc[0][1] = mfma16(a0, b1, acc[0][1]);
      acc[0][2] = mfma16(a0, b2, acc[0][2]);
      acc[0][3] = mfma16(a0, b3, acc[0][3]);
      acc[1][0] = mfma16(a1, b0, acc[1][0]);
      acc[1][1] = mfma16(a1, b1, acc[1][1]);
      acc[1][2] = mfma16(a1, b2, acc[1][2]);
      acc[1][3] = mfma16(a1, b3, acc[1][3]);
    }
  }

  const float sc = 2.0f / 1024.0f;
#pragma unroll
  for (int mi = 0; mi < 2; mi++)
#pragma unroll
    for (int ni = 0; ni < 4; ni++) {
      int n = colTile + waveN * 128 + ni * 32 + l31;
      float wv = wf[n] * sc;
#pragma unroll
      for (int reg = 0; reg < 16; reg++) {
        int rowIn = (reg & 3) + 8 * (reg >> 2) + 4 * lHalf;
        int rr = rowTile + waveM * 64 + mi * 32 + rowIn;
        int bc = rr / F_;
        int f  = rr - bc * F_;
        int t  = (f << 10) + n - 1024;
        if (t >= 0 && t < T_)
          unsafeAtomicAdd(out + (size_t)bc * T_ + t, acc[mi][ni][reg] * wv);
      }
    }
}

// ------------------------------------------------------------------ launch --
extern "C" void kernel_launch(void* const* d_in, const int* in_sizes, int n_in,
                              void* d_out, int out_size, void* d_ws, size_t ws_size,
                              hipStream_t stream) {
  const float* audio = (const float*)d_in[0];
  float* out = (float*)d_out;
  char* wsb  = (char*)d_ws;
  float*    cf  = (float*)(wsb + OFF_CF);
  _Float16* dqh = (_Float16*)(wsb + OFF_DQ);

  hipMemsetAsync(d_out, 0, (size_t)out_size * sizeof(float), stream);
  init_tables<<<(2097152 + 2048 + 255) / 256, 256, 0, stream>>>(wsb);
  fwd_mfma<<<dim3(R_ / 128, 1024 / 128), 256, 0, stream>>>(audio, wsb, cf);
  quantize<<<(B_ * F_) / 4, 256, 0, stream>>>(cf, dqh);
  inv_mfma<<<dim3(R_ / 128, 2048 / 256), 256, 0, stream>>>(wsb, out);
}